// Round 5
// baseline (3396.963 us; speedup 1.0000x reference)
//
#include <hip/hip_runtime.h>

#define NN_ 8192
#define MM_ 1024

// ============================ FPS =============================
// One block per batch, 1024 threads x 8 points each (p = j*1024 + tid).
// px/py/pz pinned in VGPRs via asm liveness (prevents the compiler from
// rematerializing the global loads every iteration — R4's 36-VGPR pathology).
// launch_bounds(1024,2): 128-VGPR budget; real occupancy is 1 block/CU anyway.
// One barrier per iteration (parity double-buffered LDS partials). The wave
// winner publishes key+coords to LDS pre-barrier; post-barrier all threads
// reduce 16 keys (argmax wave) and read coords from LDS — no dependent
// global fetch on the critical path. Exact-fp32 reference numerics.
__global__ __launch_bounds__(1024, 2) void fps_kernel(const float* __restrict__ xyz,
                                                      float* __restrict__ dout) {
  const int b = blockIdx.x;
  const int tid = threadIdx.x;
  const float* xb = xyz + (size_t)b * NN_ * 3;

  float px[8], py[8], pz[8], pd[8];
#pragma unroll
  for (int j = 0; j < 8; ++j) {
    const int p = j * 1024 + tid;
    px[j] = xb[p * 3 + 0];
    py[j] = xb[p * 3 + 1];
    pz[j] = xb[p * 3 + 2];
    pd[j] = 1e10f;
  }
  // pin the coords in registers: asm "modifies" them -> no remat from memory
#pragma unroll
  for (int j = 0; j < 8; ++j) {
    asm volatile("" : "+v"(px[j]), "+v"(py[j]), "+v"(pz[j]));
  }

  __shared__ unsigned long long s_key[2][16];  // [iteration parity][wave]
  __shared__ float s_cx[2][16], s_cy[2][16], s_cz[2][16];
  __shared__ float s_out[3 * MM_];             // centroid buffer, flushed at end

  const int lane = tid & 63;
  const int wv = tid >> 6;

  float cx = xb[0], cy = xb[1], cz = xb[2];

  for (int it = 0; it < MM_; ++it) {
    if (tid == 0) {
      s_out[it * 3 + 0] = cx;
      s_out[it * 3 + 1] = cy;
      s_out[it * 3 + 2] = cz;
    }
    if (it == MM_ - 1) break;

    // distance update + local argmax (strict > keeps smallest j on ties)
    float ld = -1.0f;
    int lj = 0;
#pragma unroll
    for (int j = 0; j < 8; ++j) {
      const float dx = __fsub_rn(px[j], cx);
      const float dy = __fsub_rn(py[j], cy);
      const float dz = __fsub_rn(pz[j], cz);
      const float dist = __fadd_rn(__fadd_rn(__fmul_rn(dx, dx), __fmul_rn(dy, dy)),
                                   __fmul_rn(dz, dz));
      const float nd = fminf(pd[j], dist);
      pd[j] = nd;
      if (nd > ld) { ld = nd; lj = j; }
    }
    // monotone packed key: max dist, tie -> smaller p (p monotone in j)
    unsigned long long key =
        ((unsigned long long)__float_as_uint(ld) << 32) |
        (unsigned int)(8191 - (lj * 1024 + tid));
    // wave butterfly argmax on the packed key
#pragma unroll
    for (int mk = 1; mk < 64; mk <<= 1) {
      const unsigned long long ok = __shfl_xor(key, mk, 64);
      key = (ok > key) ? ok : key;
    }
    // wave-winning point's owner lane publishes key + exact coords to LDS
    const int widx = 8191 - (int)(unsigned int)(key & 0xFFFFFFFFu);
    if ((widx & 1023) == tid) {
      const int j = widx >> 10;
      float wx = px[0], wy = py[0], wz = pz[0];
#pragma unroll
      for (int j2 = 1; j2 < 8; ++j2) {
        if (j2 == j) { wx = px[j2]; wy = py[j2]; wz = pz[j2]; }
      }
      s_key[it & 1][wv] = key;
      s_cx[it & 1][wv] = wx;
      s_cy[it & 1][wv] = wy;
      s_cz[it & 1][wv] = wz;
    }
    __syncthreads();
    // every thread redundantly reduces the 16 per-wave winners (argmax wave)
    unsigned long long best = s_key[it & 1][0];
    int bw = 0;
#pragma unroll
    for (int w = 1; w < 16; ++w) {
      const unsigned long long k = s_key[it & 1][w];
      if (k > best) { best = k; bw = w; }
    }
    cx = s_cx[it & 1][bw];
    cy = s_cy[it & 1][bw];
    cz = s_cz[it & 1][bw];
  }

  __syncthreads();
  float* outx = dout + (size_t)b * MM_ * 3;
  outx[tid] = s_out[tid];
  outx[1024 + tid] = s_out[1024 + tid];
  outx[2048 + tid] = s_out[2048 + tid];
}

// ============================ KNN =============================
// One wave (block of 64) per center. Each lane owns 128 points (p = jj*64+lane).
// Distances in LDS columns + 16 group-minima in regs; 32 extraction rounds of
// lexicographic (d, p) min — reproduces top_k's set with stable tie-break.
// Dot product uses an FMA chain (matches einsum/gemm inner-loop contraction);
// squared norms stay non-FMA sequential (matches elementwise-square+reduce).
__global__ __launch_bounds__(64) void knn_kernel(const float* __restrict__ xyz,
                                                 const float* __restrict__ dout,
                                                 int* __restrict__ knn) {
  __shared__ float dl[128][64];
  const int lane = threadIdx.x;
  const int center = blockIdx.x;
  const int b = center >> 10;
  const int m = center & 1023;
  const float* xb = xyz + (size_t)b * NN_ * 3;
  const float* cp = dout + (size_t)b * MM_ * 3 + m * 3;
  const float cx = cp[0], cy = cp[1], cz = cp[2];
  const float sm = __fadd_rn(__fadd_rn(__fmul_rn(cx, cx), __fmul_rn(cy, cy)),
                             __fmul_rn(cz, cz));

  float gd[16];
  int gj[16];
#pragma unroll
  for (int g = 0; g < 16; ++g) {
#pragma unroll
    for (int t = 0; t < 8; ++t) {
      const int jj = g * 8 + t;
      const int p = jj * 64 + lane;
      const float x = xb[p * 3 + 0];
      const float y = xb[p * 3 + 1];
      const float z = xb[p * 3 + 2];
      const float sn = __fadd_rn(__fadd_rn(__fmul_rn(x, x), __fmul_rn(y, y)),
                                 __fmul_rn(z, z));
      // FMA-chained contraction: fma(z,Z, fma(y,Y, x*X))
      const float dt = __fmaf_rn(cz, z, __fmaf_rn(cy, y, __fmul_rn(cx, x)));
      const float d = __fsub_rn(__fadd_rn(sm, sn), __fmul_rn(2.0f, dt));
      dl[jj][lane] = d;
      if (t == 0) { gd[g] = d; gj[g] = jj; }
      else if (d < gd[g]) { gd[g] = d; gj[g] = jj; }
    }
  }

  int out_p = 0;
  const float INF = __int_as_float(0x7f800000);
  for (int r = 0; r < 32; ++r) {
    // local best among 16 group minima (strict < keeps smallest jj)
    float ldv = gd[0];
    int ljj = gj[0];
#pragma unroll
    for (int g = 1; g < 16; ++g) {
      if (gd[g] < ldv) { ldv = gd[g]; ljj = gj[g]; }
    }
    int lp = ljj * 64 + lane;
#pragma unroll
    for (int mk = 1; mk < 64; mk <<= 1) {
      const float od = __shfl_xor(ldv, mk, 64);
      const int op = __shfl_xor(lp, mk, 64);
      const bool take = (od < ldv) || (od == ldv && op < lp);
      ldv = take ? od : ldv;
      lp = take ? op : lp;
    }
    if (lane == r) out_p = lp;
    // winner lane marks extracted slot and rebuilds that group's min
    const int wl = lp & 63;
    if (lane == wl) {
      const int jjs = lp >> 6;
      const int gs = jjs >> 3;
      dl[jjs][lane] = INF;
      float md = INF;
      int mj = 0;
#pragma unroll
      for (int t = 0; t < 8; ++t) {
        const int jj2 = gs * 8 + t;
        const float v = dl[jj2][lane];
        if (v < md) { md = v; mj = jj2; }
      }
#pragma unroll
      for (int g = 0; g < 16; ++g) {
        if (g == gs) { gd[g] = md; gj[g] = mj; }
      }
    }
  }
  if (lane < 32) knn[center * 32 + lane] = out_p;
}

// ======================= weight transpose =====================
__global__ void prep_kernel(const float* __restrict__ w1, const float* __restrict__ w2,
                            float* __restrict__ w1t, float* __restrict__ w2t) {
  const int t = blockIdx.x * 256 + threadIdx.x;
  if (t < 4096) { const int o = t >> 6, c = t & 63; w1t[c * 64 + o] = w1[t]; }
  if (t < 8192) { const int o = t >> 6, c = t & 63; w2t[c * 128 + o] = w2[t]; }
}

// ===================== layer-1 stats pass =====================
__global__ __launch_bounds__(256) void s1_kernel(const float* __restrict__ xyz,
                                                 const float* __restrict__ dout,
                                                 const int* __restrict__ knn,
                                                 const float* __restrict__ w0,
                                                 const float* __restrict__ b0,
                                                 float* __restrict__ part1) {
  const int tid = threadIdx.x;
  const int r = blockIdx.x * 256 + tid;
  const int cid = r >> 5;
  const int b = cid >> 10;
  const int m = cid & 1023;
  const int idx = knn[r];
  const float* pp = xyz + ((size_t)b * NN_ + idx) * 3;
  const float* cc = dout + ((size_t)b * MM_ + m) * 3;
  const float fx = pp[0] - cc[0];
  const float fy = pp[1] - cc[1];
  const float fz = pp[2] - cc[2];
  float acc[64];
#pragma unroll
  for (int o = 0; o < 64; ++o)
    acc[o] = fmaf(w0[o * 3 + 2], fz, fmaf(w0[o * 3 + 1], fy, fmaf(w0[o * 3 + 0], fx, b0[o])));
  const int lane = tid & 63;
  float* po = part1 + ((size_t)blockIdx.x * 4 + (tid >> 6)) * 128;
#pragma unroll
  for (int o = 0; o < 64; ++o) {
    float s = acc[o];
    float q = acc[o] * acc[o];
#pragma unroll
    for (int mk = 1; mk < 64; mk <<= 1) { s += __shfl_xor(s, mk, 64); q += __shfl_xor(q, mk, 64); }
    if (lane == 0) { po[o] = s; po[64 + o] = q; }
  }
}

// ============ BN-fold reduce: partials -> scale/shift ==========
__global__ __launch_bounds__(256) void rstat_kernel(const float* __restrict__ part, int C,
                                                    const float* __restrict__ g,
                                                    const float* __restrict__ be,
                                                    float* __restrict__ sc,
                                                    float* __restrict__ sh) {
  const int c = blockIdx.x;
  const int tid = threadIdx.x;
  float S = 0.0f, Q = 0.0f;
  for (int i = tid; i < 4096; i += 256) {
    S += part[(size_t)i * 2 * C + c];
    Q += part[(size_t)i * 2 * C + C + c];
  }
  const int lane = tid & 63;
#pragma unroll
  for (int mk = 1; mk < 64; mk <<= 1) { S += __shfl_xor(S, mk, 64); Q += __shfl_xor(Q, mk, 64); }
  __shared__ float rs[4], rq[4];
  if (lane == 0) { rs[tid >> 6] = S; rq[tid >> 6] = Q; }
  __syncthreads();
  if (tid == 0) {
    S = rs[0] + rs[1] + rs[2] + rs[3];
    Q = rq[0] + rq[1] + rq[2] + rq[3];
    const float mean = S * (1.0f / 262144.0f);
    const float var = fmaf(-mean, mean, Q * (1.0f / 262144.0f));
    const float s = g[c] * rsqrtf(var + 1e-5f);
    sc[c] = s;
    sh[c] = fmaf(-mean, s, be[c]);
  }
}

// ============ recompute chain: STAGE 2 = stats2, 3 = stats3, 4 = final ============
template <int STAGE>
__global__ __launch_bounds__(256) void chain_kernel(
    const float* __restrict__ xyz, const float* __restrict__ dout,
    const int* __restrict__ knn,
    const float* __restrict__ w0, const float* __restrict__ b0,
    const float* __restrict__ w1t, const float* __restrict__ b1,
    const float* __restrict__ w2t, const float* __restrict__ b2,
    const float* __restrict__ sc1, const float* __restrict__ sh1,
    const float* __restrict__ sc2, const float* __restrict__ sh2,
    const float* __restrict__ sc3, const float* __restrict__ sh3,
    float* __restrict__ part, float* __restrict__ outp) {
  __shared__ float f[64 * 256];  // activations, column layout [c][tid]
  const int tid = threadIdx.x;
  const int r = blockIdx.x * 256 + tid;
  const int cid = r >> 5;
  const int b = cid >> 10;
  const int m = cid & 1023;
  const int idx = knn[r];
  const float* pp = xyz + ((size_t)b * NN_ + idx) * 3;
  const float* cc = dout + ((size_t)b * MM_ + m) * 3;
  const float fx = pp[0] - cc[0];
  const float fy = pp[1] - cc[1];
  const float fz = pp[2] - cc[2];
  float acc[64];
#pragma unroll
  for (int o = 0; o < 64; ++o)
    acc[o] = fmaf(w0[o * 3 + 2], fz, fmaf(w0[o * 3 + 1], fy, fmaf(w0[o * 3 + 0], fx, b0[o])));
  // BN1 + ReLU -> LDS (own column only; no barrier needed)
#pragma unroll
  for (int o = 0; o < 64; ++o)
    f[o * 256 + tid] = fmaxf(fmaf(acc[o], sc1[o], sh1[o]), 0.0f);
  // conv2 (output-stationary, uniform weight loads)
  float a2[64];
#pragma unroll
  for (int o = 0; o < 64; ++o) a2[o] = b1[o];
#pragma unroll 4
  for (int c = 0; c < 64; ++c) {
    const float x = f[c * 256 + tid];
#pragma unroll
    for (int o = 0; o < 64; ++o) a2[o] = fmaf(w1t[c * 64 + o], x, a2[o]);
  }
  const int lane = tid & 63;
  if constexpr (STAGE == 2) {
    float* po = part + ((size_t)blockIdx.x * 4 + (tid >> 6)) * 128;
#pragma unroll
    for (int o = 0; o < 64; ++o) {
      float s = a2[o], q = a2[o] * a2[o];
#pragma unroll
      for (int mk = 1; mk < 64; mk <<= 1) { s += __shfl_xor(s, mk, 64); q += __shfl_xor(q, mk, 64); }
      if (lane == 0) { po[o] = s; po[64 + o] = q; }
    }
    return;
  }
  // BN2 + ReLU -> LDS (overwrite own column)
#pragma unroll
  for (int o = 0; o < 64; ++o)
    f[o * 256 + tid] = fmaxf(fmaf(a2[o], sc2[o], sh2[o]), 0.0f);
#pragma unroll
  for (int h = 0; h < 2; ++h) {
    float a3[64];
#pragma unroll
    for (int o = 0; o < 64; ++o) a3[o] = b2[h * 64 + o];
#pragma unroll 4
    for (int c = 0; c < 64; ++c) {
      const float x = f[c * 256 + tid];
#pragma unroll
      for (int o = 0; o < 64; ++o) a3[o] = fmaf(w2t[c * 128 + h * 64 + o], x, a3[o]);
    }
    if constexpr (STAGE == 3) {
      float* po = part + ((size_t)blockIdx.x * 4 + (tid >> 6)) * 256;
#pragma unroll
      for (int o = 0; o < 64; ++o) {
        float s = a3[o], q = a3[o] * a3[o];
#pragma unroll
        for (int mk = 1; mk < 64; mk <<= 1) { s += __shfl_xor(s, mk, 64); q += __shfl_xor(q, mk, 64); }
        if (lane == 0) { po[h * 64 + o] = s; po[128 + h * 64 + o] = q; }
      }
    } else {
      // BN3 + ReLU + max over k (32 lanes) + transposed store
#pragma unroll
      for (int o = 0; o < 64; ++o) {
        float v = fmaxf(fmaf(a3[o], sc3[h * 64 + o], sh3[h * 64 + o]), 0.0f);
#pragma unroll
        for (int mk = 1; mk < 32; mk <<= 1) v = fmaxf(v, __shfl_xor(v, mk, 64));
        if ((lane & 31) == 0)
          outp[24576 + (size_t)b * 131072 + (size_t)(h * 64 + o) * 1024 + m] = v;
      }
    }
  }
}

// ============================ launch =============================
extern "C" void kernel_launch(void* const* d_in, const int* in_sizes, int n_in,
                              void* d_out, int out_size, void* d_ws, size_t ws_size,
                              hipStream_t stream) {
  const float* xyz = (const float*)d_in[0];
  const float* w0 = (const float*)d_in[1];
  const float* b0 = (const float*)d_in[2];
  const float* g0 = (const float*)d_in[3];
  const float* be0 = (const float*)d_in[4];
  const float* w1 = (const float*)d_in[5];
  const float* b1 = (const float*)d_in[6];
  const float* g1 = (const float*)d_in[7];
  const float* be1 = (const float*)d_in[8];
  const float* w2 = (const float*)d_in[9];
  const float* b2 = (const float*)d_in[10];
  const float* g2 = (const float*)d_in[11];
  const float* be2 = (const float*)d_in[12];
  float* out = (float*)d_out;
  char* ws = (char*)d_ws;

  // ws layout (~9.5 MB total):
  int* knn = (int*)ws;                                   // [8192][32] ints
  float* part1 = (float*)(ws + (size_t)1 * (1 << 20));   // [4096][128]
  float* part2 = (float*)(ws + (size_t)3 * (1 << 20));   // [4096][128]
  float* part3 = (float*)(ws + (size_t)5 * (1 << 20));   // [4096][256]
  float* sc1 = (float*)(ws + (size_t)9 * (1 << 20));
  float* sh1 = sc1 + 64;
  float* sc2 = sh1 + 64;
  float* sh2 = sc2 + 64;
  float* sc3 = sh2 + 64;
  float* sh3 = sc3 + 128;
  float* w1t = sh3 + 128;
  float* w2t = w1t + 4096;

  fps_kernel<<<8, 1024, 0, stream>>>(xyz, out);
  knn_kernel<<<8192, 64, 0, stream>>>(xyz, out, knn);
  prep_kernel<<<32, 256, 0, stream>>>(w1, w2, w1t, w2t);
  s1_kernel<<<1024, 256, 0, stream>>>(xyz, out, knn, w0, b0, part1);
  rstat_kernel<<<64, 256, 0, stream>>>(part1, 64, g0, be0, sc1, sh1);
  chain_kernel<2><<<1024, 256, 0, stream>>>(xyz, out, knn, w0, b0, w1t, b1, w2t, b2,
                                            sc1, sh1, sc2, sh2, sc3, sh3, part2, out);
  rstat_kernel<<<64, 256, 0, stream>>>(part2, 64, g1, be1, sc2, sh2);
  chain_kernel<3><<<1024, 256, 0, stream>>>(xyz, out, knn, w0, b0, w1t, b1, w2t, b2,
                                            sc1, sh1, sc2, sh2, sc3, sh3, part3, out);
  rstat_kernel<<<128, 256, 0, stream>>>(part3, 128, g2, be2, sc3, sh3);
  chain_kernel<4><<<1024, 256, 0, stream>>>(xyz, out, knn, w0, b0, w1t, b1, w2t, b2,
                                            sc1, sh1, sc2, sh2, sc3, sh3, part3, out);
}

// Round 6
// 2724.221 us; speedup vs baseline: 1.2469x; 1.2469x over previous
//
#include <hip/hip_runtime.h>

#define NN_ 8192
#define MM_ 1024

// ============================ FPS =============================
// One block per batch, 1024 threads x 8 points each.
// Point coords live in LDS SoA arrays (explicit ds_read_b128 each iteration —
// no register-residency gamble, no remat, no scratch; R4/R5 pathology gone).
// Running min-distances pd0..pd7 are NAMED SCALARS -> guaranteed registers.
// Thread t owns points {4t..4t+3} and {4096+4t..4096+4t+3} (float4-aligned
// SoA reads). One barrier per iteration; parity double-buffered per-wave key
// partials; winner coords come from LDS by index (broadcast read, exact
// copies of the input values). Exact-fp32 reference numerics preserved.
__global__ __launch_bounds__(1024) void fps_kernel(const float* __restrict__ xyz,
                                                   float* __restrict__ dout) {
  const int b = blockIdx.x;
  const int tid = threadIdx.x;
  const float* xb = xyz + (size_t)b * NN_ * 3;

  __shared__ float s_x[NN_], s_y[NN_], s_z[NN_];   // 96 KB SoA coords
  __shared__ float s_out[3 * MM_];                 // 12 KB centroid buffer
  __shared__ unsigned long long s_key[2][16];      // [iter parity][wave]

  // one-time load: interleaved global -> SoA LDS
  for (int i = tid; i < NN_; i += 1024) {
    s_x[i] = xb[3 * i + 0];
    s_y[i] = xb[3 * i + 1];
    s_z[i] = xb[3 * i + 2];
  }

  float pd0 = 1e10f, pd1 = 1e10f, pd2 = 1e10f, pd3 = 1e10f;
  float pd4 = 1e10f, pd5 = 1e10f, pd6 = 1e10f, pd7 = 1e10f;

  __syncthreads();

  const int lane = tid & 63;
  const int wv = tid >> 6;
  const int base0 = 4 * tid;
  const int base1 = NN_ / 2 + 4 * tid;

  float cx = s_x[0], cy = s_y[0], cz = s_z[0];  // exact copies of xb[0..2]

  for (int it = 0; it < MM_; ++it) {
    if (tid == 0) {
      s_out[it * 3 + 0] = cx;
      s_out[it * 3 + 1] = cy;
      s_out[it * 3 + 2] = cz;
    }
    if (it == MM_ - 1) break;

    // ---- distance update + local argmax over 8 owned points ----
    float ld = -1.0f;
    int lp = 0;

    const float4 xa = *(const float4*)&s_x[base0];
    const float4 ya = *(const float4*)&s_y[base0];
    const float4 za = *(const float4*)&s_z[base0];
#define FPS_UPD(PD, PX, PY, PZ, PIDX)                                          \
    {                                                                          \
      const float dx = __fsub_rn(PX, cx);                                      \
      const float dy = __fsub_rn(PY, cy);                                      \
      const float dz = __fsub_rn(PZ, cz);                                      \
      const float dist = __fadd_rn(                                            \
          __fadd_rn(__fmul_rn(dx, dx), __fmul_rn(dy, dy)), __fmul_rn(dz, dz)); \
      const float nd = fminf(PD, dist);                                        \
      PD = nd;                                                                 \
      if (nd > ld) { ld = nd; lp = (PIDX); }                                   \
    }
    FPS_UPD(pd0, xa.x, ya.x, za.x, base0 + 0)
    FPS_UPD(pd1, xa.y, ya.y, za.y, base0 + 1)
    FPS_UPD(pd2, xa.z, ya.z, za.z, base0 + 2)
    FPS_UPD(pd3, xa.w, ya.w, za.w, base0 + 3)
    const float4 xbv = *(const float4*)&s_x[base1];
    const float4 ybv = *(const float4*)&s_y[base1];
    const float4 zbv = *(const float4*)&s_z[base1];
    FPS_UPD(pd4, xbv.x, ybv.x, zbv.x, base1 + 0)
    FPS_UPD(pd5, xbv.y, ybv.y, zbv.y, base1 + 1)
    FPS_UPD(pd6, xbv.z, ybv.z, zbv.z, base1 + 2)
    FPS_UPD(pd7, xbv.w, ybv.w, zbv.w, base1 + 3)
#undef FPS_UPD

    // monotone packed key: max dist, tie -> smaller p
    unsigned long long key =
        ((unsigned long long)__float_as_uint(ld) << 32) |
        (unsigned int)(8191 - lp);
    // wave butterfly argmax on the packed key
#pragma unroll
    for (int mk = 1; mk < 64; mk <<= 1) {
      const unsigned long long ok = __shfl_xor(key, mk, 64);
      key = (ok > key) ? ok : key;
    }
    if (lane == 0) s_key[it & 1][wv] = key;
    __syncthreads();
    // every thread redundantly reduces the 16 per-wave winners
    unsigned long long best = s_key[it & 1][0];
#pragma unroll
    for (int w = 1; w < 16; ++w) {
      const unsigned long long k = s_key[it & 1][w];
      best = (k > best) ? k : best;
    }
    const int win = 8191 - (int)(unsigned int)(best & 0xFFFFFFFFu);
    // new centroid: exact coords via broadcast LDS read
    cx = s_x[win];
    cy = s_y[win];
    cz = s_z[win];
  }

  __syncthreads();
  float* outx = dout + (size_t)b * MM_ * 3;
  outx[tid] = s_out[tid];
  outx[1024 + tid] = s_out[1024 + tid];
  outx[2048 + tid] = s_out[2048 + tid];
}

// ============================ KNN =============================
// One wave (block of 64) per center. Each lane owns 128 points (p = jj*64+lane).
// Distances in LDS columns + 16 group-minima in regs; 32 extraction rounds of
// lexicographic (d, p) min — reproduces top_k's set with stable tie-break.
// Dot product uses an FMA chain (matches einsum/gemm inner-loop contraction);
// squared norms stay non-FMA sequential (matches elementwise-square+reduce).
__global__ __launch_bounds__(64) void knn_kernel(const float* __restrict__ xyz,
                                                 const float* __restrict__ dout,
                                                 int* __restrict__ knn) {
  __shared__ float dl[128][64];
  const int lane = threadIdx.x;
  const int center = blockIdx.x;
  const int b = center >> 10;
  const int m = center & 1023;
  const float* xb = xyz + (size_t)b * NN_ * 3;
  const float* cp = dout + (size_t)b * MM_ * 3 + m * 3;
  const float cx = cp[0], cy = cp[1], cz = cp[2];
  const float sm = __fadd_rn(__fadd_rn(__fmul_rn(cx, cx), __fmul_rn(cy, cy)),
                             __fmul_rn(cz, cz));

  float gd[16];
  int gj[16];
#pragma unroll
  for (int g = 0; g < 16; ++g) {
#pragma unroll
    for (int t = 0; t < 8; ++t) {
      const int jj = g * 8 + t;
      const int p = jj * 64 + lane;
      const float x = xb[p * 3 + 0];
      const float y = xb[p * 3 + 1];
      const float z = xb[p * 3 + 2];
      const float sn = __fadd_rn(__fadd_rn(__fmul_rn(x, x), __fmul_rn(y, y)),
                                 __fmul_rn(z, z));
      // FMA-chained contraction: fma(z,Z, fma(y,Y, x*X))
      const float dt = __fmaf_rn(cz, z, __fmaf_rn(cy, y, __fmul_rn(cx, x)));
      const float d = __fsub_rn(__fadd_rn(sm, sn), __fmul_rn(2.0f, dt));
      dl[jj][lane] = d;
      if (t == 0) { gd[g] = d; gj[g] = jj; }
      else if (d < gd[g]) { gd[g] = d; gj[g] = jj; }
    }
  }

  int out_p = 0;
  const float INF = __int_as_float(0x7f800000);
  for (int r = 0; r < 32; ++r) {
    // local best among 16 group minima (strict < keeps smallest jj)
    float ldv = gd[0];
    int ljj = gj[0];
#pragma unroll
    for (int g = 1; g < 16; ++g) {
      if (gd[g] < ldv) { ldv = gd[g]; ljj = gj[g]; }
    }
    int lp = ljj * 64 + lane;
#pragma unroll
    for (int mk = 1; mk < 64; mk <<= 1) {
      const float od = __shfl_xor(ldv, mk, 64);
      const int op = __shfl_xor(lp, mk, 64);
      const bool take = (od < ldv) || (od == ldv && op < lp);
      ldv = take ? od : ldv;
      lp = take ? op : lp;
    }
    if (lane == r) out_p = lp;
    // winner lane marks extracted slot and rebuilds that group's min
    const int wl = lp & 63;
    if (lane == wl) {
      const int jjs = lp >> 6;
      const int gs = jjs >> 3;
      dl[jjs][lane] = INF;
      float md = INF;
      int mj = 0;
#pragma unroll
      for (int t = 0; t < 8; ++t) {
        const int jj2 = gs * 8 + t;
        const float v = dl[jj2][lane];
        if (v < md) { md = v; mj = jj2; }
      }
#pragma unroll
      for (int g = 0; g < 16; ++g) {
        if (g == gs) { gd[g] = md; gj[g] = mj; }
      }
    }
  }
  if (lane < 32) knn[center * 32 + lane] = out_p;
}

// ======================= weight transpose =====================
__global__ void prep_kernel(const float* __restrict__ w1, const float* __restrict__ w2,
                            float* __restrict__ w1t, float* __restrict__ w2t) {
  const int t = blockIdx.x * 256 + threadIdx.x;
  if (t < 4096) { const int o = t >> 6, c = t & 63; w1t[c * 64 + o] = w1[t]; }
  if (t < 8192) { const int o = t >> 6, c = t & 63; w2t[c * 128 + o] = w2[t]; }
}

// ===================== layer-1 stats pass =====================
__global__ __launch_bounds__(256) void s1_kernel(const float* __restrict__ xyz,
                                                 const float* __restrict__ dout,
                                                 const int* __restrict__ knn,
                                                 const float* __restrict__ w0,
                                                 const float* __restrict__ b0,
                                                 float* __restrict__ part1) {
  const int tid = threadIdx.x;
  const int r = blockIdx.x * 256 + tid;
  const int cid = r >> 5;
  const int b = cid >> 10;
  const int m = cid & 1023;
  const int idx = knn[r];
  const float* pp = xyz + ((size_t)b * NN_ + idx) * 3;
  const float* cc = dout + ((size_t)b * MM_ + m) * 3;
  const float fx = pp[0] - cc[0];
  const float fy = pp[1] - cc[1];
  const float fz = pp[2] - cc[2];
  float acc[64];
#pragma unroll
  for (int o = 0; o < 64; ++o)
    acc[o] = fmaf(w0[o * 3 + 2], fz, fmaf(w0[o * 3 + 1], fy, fmaf(w0[o * 3 + 0], fx, b0[o])));
  const int lane = tid & 63;
  float* po = part1 + ((size_t)blockIdx.x * 4 + (tid >> 6)) * 128;
#pragma unroll
  for (int o = 0; o < 64; ++o) {
    float s = acc[o];
    float q = acc[o] * acc[o];
#pragma unroll
    for (int mk = 1; mk < 64; mk <<= 1) { s += __shfl_xor(s, mk, 64); q += __shfl_xor(q, mk, 64); }
    if (lane == 0) { po[o] = s; po[64 + o] = q; }
  }
}

// ============ BN-fold reduce: partials -> scale/shift ==========
__global__ __launch_bounds__(256) void rstat_kernel(const float* __restrict__ part, int C,
                                                    const float* __restrict__ g,
                                                    const float* __restrict__ be,
                                                    float* __restrict__ sc,
                                                    float* __restrict__ sh) {
  const int c = blockIdx.x;
  const int tid = threadIdx.x;
  float S = 0.0f, Q = 0.0f;
  for (int i = tid; i < 4096; i += 256) {
    S += part[(size_t)i * 2 * C + c];
    Q += part[(size_t)i * 2 * C + C + c];
  }
  const int lane = tid & 63;
#pragma unroll
  for (int mk = 1; mk < 64; mk <<= 1) { S += __shfl_xor(S, mk, 64); Q += __shfl_xor(Q, mk, 64); }
  __shared__ float rs[4], rq[4];
  if (lane == 0) { rs[tid >> 6] = S; rq[tid >> 6] = Q; }
  __syncthreads();
  if (tid == 0) {
    S = rs[0] + rs[1] + rs[2] + rs[3];
    Q = rq[0] + rq[1] + rq[2] + rq[3];
    const float mean = S * (1.0f / 262144.0f);
    const float var = fmaf(-mean, mean, Q * (1.0f / 262144.0f));
    const float s = g[c] * rsqrtf(var + 1e-5f);
    sc[c] = s;
    sh[c] = fmaf(-mean, s, be[c]);
  }
}

// ============ recompute chain: STAGE 2 = stats2, 3 = stats3, 4 = final ============
template <int STAGE>
__global__ __launch_bounds__(256) void chain_kernel(
    const float* __restrict__ xyz, const float* __restrict__ dout,
    const int* __restrict__ knn,
    const float* __restrict__ w0, const float* __restrict__ b0,
    const float* __restrict__ w1t, const float* __restrict__ b1,
    const float* __restrict__ w2t, const float* __restrict__ b2,
    const float* __restrict__ sc1, const float* __restrict__ sh1,
    const float* __restrict__ sc2, const float* __restrict__ sh2,
    const float* __restrict__ sc3, const float* __restrict__ sh3,
    float* __restrict__ part, float* __restrict__ outp) {
  __shared__ float f[64 * 256];  // activations, column layout [c][tid]
  const int tid = threadIdx.x;
  const int r = blockIdx.x * 256 + tid;
  const int cid = r >> 5;
  const int b = cid >> 10;
  const int m = cid & 1023;
  const int idx = knn[r];
  const float* pp = xyz + ((size_t)b * NN_ + idx) * 3;
  const float* cc = dout + ((size_t)b * MM_ + m) * 3;
  const float fx = pp[0] - cc[0];
  const float fy = pp[1] - cc[1];
  const float fz = pp[2] - cc[2];
  float acc[64];
#pragma unroll
  for (int o = 0; o < 64; ++o)
    acc[o] = fmaf(w0[o * 3 + 2], fz, fmaf(w0[o * 3 + 1], fy, fmaf(w0[o * 3 + 0], fx, b0[o])));
  // BN1 + ReLU -> LDS (own column only; no barrier needed)
#pragma unroll
  for (int o = 0; o < 64; ++o)
    f[o * 256 + tid] = fmaxf(fmaf(acc[o], sc1[o], sh1[o]), 0.0f);
  // conv2 (output-stationary, uniform weight loads)
  float a2[64];
#pragma unroll
  for (int o = 0; o < 64; ++o) a2[o] = b1[o];
#pragma unroll 4
  for (int c = 0; c < 64; ++c) {
    const float x = f[c * 256 + tid];
#pragma unroll
    for (int o = 0; o < 64; ++o) a2[o] = fmaf(w1t[c * 64 + o], x, a2[o]);
  }
  const int lane = tid & 63;
  if constexpr (STAGE == 2) {
    float* po = part + ((size_t)blockIdx.x * 4 + (tid >> 6)) * 128;
#pragma unroll
    for (int o = 0; o < 64; ++o) {
      float s = a2[o], q = a2[o] * a2[o];
#pragma unroll
      for (int mk = 1; mk < 64; mk <<= 1) { s += __shfl_xor(s, mk, 64); q += __shfl_xor(q, mk, 64); }
      if (lane == 0) { po[o] = s; po[64 + o] = q; }
    }
    return;
  }
  // BN2 + ReLU -> LDS (overwrite own column)
#pragma unroll
  for (int o = 0; o < 64; ++o)
    f[o * 256 + tid] = fmaxf(fmaf(a2[o], sc2[o], sh2[o]), 0.0f);
#pragma unroll
  for (int h = 0; h < 2; ++h) {
    float a3[64];
#pragma unroll
    for (int o = 0; o < 64; ++o) a3[o] = b2[h * 64 + o];
#pragma unroll 4
    for (int c = 0; c < 64; ++c) {
      const float x = f[c * 256 + tid];
#pragma unroll
      for (int o = 0; o < 64; ++o) a3[o] = fmaf(w2t[c * 128 + h * 64 + o], x, a3[o]);
    }
    if constexpr (STAGE == 3) {
      float* po = part + ((size_t)blockIdx.x * 4 + (tid >> 6)) * 256;
#pragma unroll
      for (int o = 0; o < 64; ++o) {
        float s = a3[o], q = a3[o] * a3[o];
#pragma unroll
        for (int mk = 1; mk < 64; mk <<= 1) { s += __shfl_xor(s, mk, 64); q += __shfl_xor(q, mk, 64); }
        if (lane == 0) { po[h * 64 + o] = s; po[128 + h * 64 + o] = q; }
      }
    } else {
      // BN3 + ReLU + max over k (32 lanes) + transposed store
#pragma unroll
      for (int o = 0; o < 64; ++o) {
        float v = fmaxf(fmaf(a3[o], sc3[h * 64 + o], sh3[h * 64 + o]), 0.0f);
#pragma unroll
        for (int mk = 1; mk < 32; mk <<= 1) v = fmaxf(v, __shfl_xor(v, mk, 64));
        if ((lane & 31) == 0)
          outp[24576 + (size_t)b * 131072 + (size_t)(h * 64 + o) * 1024 + m] = v;
      }
    }
  }
}

// ============================ launch =============================
extern "C" void kernel_launch(void* const* d_in, const int* in_sizes, int n_in,
                              void* d_out, int out_size, void* d_ws, size_t ws_size,
                              hipStream_t stream) {
  const float* xyz = (const float*)d_in[0];
  const float* w0 = (const float*)d_in[1];
  const float* b0 = (const float*)d_in[2];
  const float* g0 = (const float*)d_in[3];
  const float* be0 = (const float*)d_in[4];
  const float* w1 = (const float*)d_in[5];
  const float* b1 = (const float*)d_in[6];
  const float* g1 = (const float*)d_in[7];
  const float* be1 = (const float*)d_in[8];
  const float* w2 = (const float*)d_in[9];
  const float* b2 = (const float*)d_in[10];
  const float* g2 = (const float*)d_in[11];
  const float* be2 = (const float*)d_in[12];
  float* out = (float*)d_out;
  char* ws = (char*)d_ws;

  // ws layout (~9.5 MB total):
  int* knn = (int*)ws;                                   // [8192][32] ints
  float* part1 = (float*)(ws + (size_t)1 * (1 << 20));   // [4096][128]
  float* part2 = (float*)(ws + (size_t)3 * (1 << 20));   // [4096][128]
  float* part3 = (float*)(ws + (size_t)5 * (1 << 20));   // [4096][256]
  float* sc1 = (float*)(ws + (size_t)9 * (1 << 20));
  float* sh1 = sc1 + 64;
  float* sc2 = sh1 + 64;
  float* sh2 = sc2 + 64;
  float* sc3 = sh2 + 64;
  float* sh3 = sc3 + 128;
  float* w1t = sh3 + 128;
  float* w2t = w1t + 4096;

  fps_kernel<<<8, 1024, 0, stream>>>(xyz, out);
  knn_kernel<<<8192, 64, 0, stream>>>(xyz, out, knn);
  prep_kernel<<<32, 256, 0, stream>>>(w1, w2, w1t, w2t);
  s1_kernel<<<1024, 256, 0, stream>>>(xyz, out, knn, w0, b0, part1);
  rstat_kernel<<<64, 256, 0, stream>>>(part1, 64, g0, be0, sc1, sh1);
  chain_kernel<2><<<1024, 256, 0, stream>>>(xyz, out, knn, w0, b0, w1t, b1, w2t, b2,
                                            sc1, sh1, sc2, sh2, sc3, sh3, part2, out);
  rstat_kernel<<<64, 256, 0, stream>>>(part2, 64, g1, be1, sc2, sh2);
  chain_kernel<3><<<1024, 256, 0, stream>>>(xyz, out, knn, w0, b0, w1t, b1, w2t, b2,
                                            sc1, sh1, sc2, sh2, sc3, sh3, part3, out);
  rstat_kernel<<<128, 256, 0, stream>>>(part3, 128, g2, be2, sc3, sh3);
  chain_kernel<4><<<1024, 256, 0, stream>>>(xyz, out, knn, w0, b0, w1t, b1, w2t, b2,
                                            sc1, sh1, sc2, sh2, sc3, sh3, part3, out);
}

// Round 7
// 1722.215 us; speedup vs baseline: 1.9724x; 1.5818x over previous
//
#include <hip/hip_runtime.h>

#define NN_ 8192
#define MM_ 1024

// DPP-based wave64 max-reduce step on a packed u64 key (pure VALU, no LDS).
// ctrl: 0x111/0x112/0x114/0x118 = row_shr 1/2/4/8, 0x142 = bcast15, 0x143 = bcast31.
// After the 6-step chain, lane 63 holds the wave-wide max key.
#define DPP_UMAX64(K, CTRL)                                                     \
  {                                                                             \
    const int lo_ = (int)(unsigned int)(K);                                     \
    const int hi_ = (int)(unsigned int)((K) >> 32);                             \
    const int slo_ = __builtin_amdgcn_update_dpp(lo_, lo_, (CTRL), 0xf, 0xf, false); \
    const int shi_ = __builtin_amdgcn_update_dpp(hi_, hi_, (CTRL), 0xf, 0xf, false); \
    const unsigned long long ok_ =                                              \
        ((unsigned long long)(unsigned int)shi_ << 32) | (unsigned int)slo_;    \
    (K) = (ok_ > (K)) ? ok_ : (K);                                              \
  }

// ============================ FPS =============================
// One block per batch, 256 threads x 32 points each (p = 32*tid + j).
// Coords held in REGISTERS: 24 float4 loaded from LDS once before the loop,
// followed by an asm memory clobber -> the compiler cannot legally sink or
// rematerialize those LDS loads into the loop (must keep them register-
// resident). launch_bounds(256,1) gives a 256-VGPR budget -> no spill.
// Wave argmax = DPP max chain on packed u64 key (VALU only, zero LDS-pipe
// shuffles). Cross-wave = 2x ds_read_b128 + 3 u64 selects, one barrier/iter
// (parity double-buffered). Winner coords via broadcast LDS reads (exact
// copies). Centroids buffered in LDS, flushed once. Exact-fp32 numerics:
// rn ops, sequential (x+y)+z, first-index argmax ties.
__global__ __launch_bounds__(256, 1) void fps_kernel(const float* __restrict__ xyz,
                                                     float* __restrict__ dout) {
  const int b = blockIdx.x;
  const int tid = threadIdx.x;
  const float* xb = xyz + (size_t)b * NN_ * 3;

  __shared__ float s_x[NN_], s_y[NN_], s_z[NN_];          // 96 KB SoA coords
  __shared__ float s_out[3 * MM_];                        // 12 KB centroids
  __shared__ __align__(16) unsigned long long s_key[2][4];  // [parity][wave]

  // one-time: interleaved global -> SoA LDS
  for (int i = tid; i < NN_; i += 256) {
    s_x[i] = xb[3 * i + 0];
    s_y[i] = xb[3 * i + 1];
    s_z[i] = xb[3 * i + 2];
  }
  __syncthreads();

  // 32 owned points -> registers (8 float4 per axis)
  const int base = 32 * tid;
  float4 rx[8], ry[8], rz[8];
#pragma unroll
  for (int q = 0; q < 8; ++q) {
    rx[q] = *(const float4*)&s_x[base + 4 * q];
    ry[q] = *(const float4*)&s_y[base + 4 * q];
    rz[q] = *(const float4*)&s_z[base + 4 * q];
  }
  // Compiler barrier: LDS must be assumed modified after this point, so the
  // loads above cannot be sunk/remat'ed into the loop. Values stay in VGPRs.
  asm volatile("" ::: "memory");

  float pd[32];
#pragma unroll
  for (int j = 0; j < 32; ++j) pd[j] = 1e10f;

  const int lane = tid & 63;
  const int wv = tid >> 6;

  float cx = s_x[0], cy = s_y[0], cz = s_z[0];  // exact copies of xb[0..2]

  for (int it = 0; it < MM_; ++it) {
    if (tid == 0) {
      s_out[it * 3 + 0] = cx;
      s_out[it * 3 + 1] = cy;
      s_out[it * 3 + 2] = cz;
    }
    if (it == MM_ - 1) break;

    // ---- distance update + local argmax over 32 register-resident points ----
    float ld = -1.0f;
    int lj = 0;
#define FPS_UPD(PX, PY, PZ, J)                                                 \
    {                                                                          \
      const float dx = __fsub_rn(PX, cx);                                      \
      const float dy = __fsub_rn(PY, cy);                                      \
      const float dz = __fsub_rn(PZ, cz);                                      \
      const float dist = __fadd_rn(                                            \
          __fadd_rn(__fmul_rn(dx, dx), __fmul_rn(dy, dy)), __fmul_rn(dz, dz)); \
      const float nd = fminf(pd[J], dist);                                     \
      pd[J] = nd;                                                              \
      if (nd > ld) { ld = nd; lj = (J); }                                      \
    }
#pragma unroll
    for (int q = 0; q < 8; ++q) {
      FPS_UPD(rx[q].x, ry[q].x, rz[q].x, 4 * q + 0)
      FPS_UPD(rx[q].y, ry[q].y, rz[q].y, 4 * q + 1)
      FPS_UPD(rx[q].z, ry[q].z, rz[q].z, 4 * q + 2)
      FPS_UPD(rx[q].w, ry[q].w, rz[q].w, 4 * q + 3)
    }
#undef FPS_UPD

    // monotone packed key: max dist, tie -> smaller p (p = base + lj)
    unsigned long long key =
        ((unsigned long long)__float_as_uint(ld) << 32) |
        (unsigned int)(8191 - (base + lj));
    // wave-wide DPP max chain (VALU only); lane 63 ends with the wave max
    DPP_UMAX64(key, 0x111)
    DPP_UMAX64(key, 0x112)
    DPP_UMAX64(key, 0x114)
    DPP_UMAX64(key, 0x118)
    DPP_UMAX64(key, 0x142)
    DPP_UMAX64(key, 0x143)
    if (lane == 63) s_key[it & 1][wv] = key;
    __syncthreads();

    // cross-wave: 2x b128 reads + 3 u64 selects (redundant per thread)
    const ulonglong2 ka = *(const ulonglong2*)&s_key[it & 1][0];
    const ulonglong2 kb = *(const ulonglong2*)&s_key[it & 1][2];
    unsigned long long best = (ka.x > ka.y) ? ka.x : ka.y;
    const unsigned long long bb = (kb.x > kb.y) ? kb.x : kb.y;
    best = (best > bb) ? best : bb;
    const int win = 8191 - (int)(unsigned int)(best & 0xFFFFFFFFu);
    // new centroid: exact coords via broadcast LDS reads
    cx = s_x[win];
    cy = s_y[win];
    cz = s_z[win];
  }

  __syncthreads();
  float* outx = dout + (size_t)b * MM_ * 3;
#pragma unroll
  for (int i = 0; i < 12; ++i) outx[i * 256 + tid] = s_out[i * 256 + tid];
}

// ============================ KNN =============================
// One wave (block of 64) per center. Each lane owns 128 points (p = jj*64+lane).
// Distances in LDS columns + 16 group-minima in regs; 32 extraction rounds of
// lexicographic (d, p) min — reproduces top_k's set with stable tie-break.
// Dot product uses an FMA chain (matches einsum/gemm inner-loop contraction);
// squared norms stay non-FMA sequential (matches elementwise-square+reduce).
__global__ __launch_bounds__(64) void knn_kernel(const float* __restrict__ xyz,
                                                 const float* __restrict__ dout,
                                                 int* __restrict__ knn) {
  __shared__ float dl[128][64];
  const int lane = threadIdx.x;
  const int center = blockIdx.x;
  const int b = center >> 10;
  const int m = center & 1023;
  const float* xb = xyz + (size_t)b * NN_ * 3;
  const float* cp = dout + (size_t)b * MM_ * 3 + m * 3;
  const float cx = cp[0], cy = cp[1], cz = cp[2];
  const float sm = __fadd_rn(__fadd_rn(__fmul_rn(cx, cx), __fmul_rn(cy, cy)),
                             __fmul_rn(cz, cz));

  float gd[16];
  int gj[16];
#pragma unroll
  for (int g = 0; g < 16; ++g) {
#pragma unroll
    for (int t = 0; t < 8; ++t) {
      const int jj = g * 8 + t;
      const int p = jj * 64 + lane;
      const float x = xb[p * 3 + 0];
      const float y = xb[p * 3 + 1];
      const float z = xb[p * 3 + 2];
      const float sn = __fadd_rn(__fadd_rn(__fmul_rn(x, x), __fmul_rn(y, y)),
                                 __fmul_rn(z, z));
      // FMA-chained contraction: fma(z,Z, fma(y,Y, x*X))
      const float dt = __fmaf_rn(cz, z, __fmaf_rn(cy, y, __fmul_rn(cx, x)));
      const float d = __fsub_rn(__fadd_rn(sm, sn), __fmul_rn(2.0f, dt));
      dl[jj][lane] = d;
      if (t == 0) { gd[g] = d; gj[g] = jj; }
      else if (d < gd[g]) { gd[g] = d; gj[g] = jj; }
    }
  }

  int out_p = 0;
  const float INF = __int_as_float(0x7f800000);
  for (int r = 0; r < 32; ++r) {
    // local best among 16 group minima (strict < keeps smallest jj)
    float ldv = gd[0];
    int ljj = gj[0];
#pragma unroll
    for (int g = 1; g < 16; ++g) {
      if (gd[g] < ldv) { ldv = gd[g]; ljj = gj[g]; }
    }
    int lp = ljj * 64 + lane;
#pragma unroll
    for (int mk = 1; mk < 64; mk <<= 1) {
      const float od = __shfl_xor(ldv, mk, 64);
      const int op = __shfl_xor(lp, mk, 64);
      const bool take = (od < ldv) || (od == ldv && op < lp);
      ldv = take ? od : ldv;
      lp = take ? op : lp;
    }
    if (lane == r) out_p = lp;
    // winner lane marks extracted slot and rebuilds that group's min
    const int wl = lp & 63;
    if (lane == wl) {
      const int jjs = lp >> 6;
      const int gs = jjs >> 3;
      dl[jjs][lane] = INF;
      float md = INF;
      int mj = 0;
#pragma unroll
      for (int t = 0; t < 8; ++t) {
        const int jj2 = gs * 8 + t;
        const float v = dl[jj2][lane];
        if (v < md) { md = v; mj = jj2; }
      }
#pragma unroll
      for (int g = 0; g < 16; ++g) {
        if (g == gs) { gd[g] = md; gj[g] = mj; }
      }
    }
  }
  if (lane < 32) knn[center * 32 + lane] = out_p;
}

// ======================= weight transpose =====================
__global__ void prep_kernel(const float* __restrict__ w1, const float* __restrict__ w2,
                            float* __restrict__ w1t, float* __restrict__ w2t) {
  const int t = blockIdx.x * 256 + threadIdx.x;
  if (t < 4096) { const int o = t >> 6, c = t & 63; w1t[c * 64 + o] = w1[t]; }
  if (t < 8192) { const int o = t >> 6, c = t & 63; w2t[c * 128 + o] = w2[t]; }
}

// ===================== layer-1 stats pass =====================
__global__ __launch_bounds__(256) void s1_kernel(const float* __restrict__ xyz,
                                                 const float* __restrict__ dout,
                                                 const int* __restrict__ knn,
                                                 const float* __restrict__ w0,
                                                 const float* __restrict__ b0,
                                                 float* __restrict__ part1) {
  const int tid = threadIdx.x;
  const int r = blockIdx.x * 256 + tid;
  const int cid = r >> 5;
  const int b = cid >> 10;
  const int m = cid & 1023;
  const int idx = knn[r];
  const float* pp = xyz + ((size_t)b * NN_ + idx) * 3;
  const float* cc = dout + ((size_t)b * MM_ + m) * 3;
  const float fx = pp[0] - cc[0];
  const float fy = pp[1] - cc[1];
  const float fz = pp[2] - cc[2];
  float acc[64];
#pragma unroll
  for (int o = 0; o < 64; ++o)
    acc[o] = fmaf(w0[o * 3 + 2], fz, fmaf(w0[o * 3 + 1], fy, fmaf(w0[o * 3 + 0], fx, b0[o])));
  const int lane = tid & 63;
  float* po = part1 + ((size_t)blockIdx.x * 4 + (tid >> 6)) * 128;
#pragma unroll
  for (int o = 0; o < 64; ++o) {
    float s = acc[o];
    float q = acc[o] * acc[o];
#pragma unroll
    for (int mk = 1; mk < 64; mk <<= 1) { s += __shfl_xor(s, mk, 64); q += __shfl_xor(q, mk, 64); }
    if (lane == 0) { po[o] = s; po[64 + o] = q; }
  }
}

// ============ BN-fold reduce: partials -> scale/shift ==========
__global__ __launch_bounds__(256) void rstat_kernel(const float* __restrict__ part, int C,
                                                    const float* __restrict__ g,
                                                    const float* __restrict__ be,
                                                    float* __restrict__ sc,
                                                    float* __restrict__ sh) {
  const int c = blockIdx.x;
  const int tid = threadIdx.x;
  float S = 0.0f, Q = 0.0f;
  for (int i = tid; i < 4096; i += 256) {
    S += part[(size_t)i * 2 * C + c];
    Q += part[(size_t)i * 2 * C + C + c];
  }
  const int lane = tid & 63;
#pragma unroll
  for (int mk = 1; mk < 64; mk <<= 1) { S += __shfl_xor(S, mk, 64); Q += __shfl_xor(Q, mk, 64); }
  __shared__ float rs[4], rq[4];
  if (lane == 0) { rs[tid >> 6] = S; rq[tid >> 6] = Q; }
  __syncthreads();
  if (tid == 0) {
    S = rs[0] + rs[1] + rs[2] + rs[3];
    Q = rq[0] + rq[1] + rq[2] + rq[3];
    const float mean = S * (1.0f / 262144.0f);
    const float var = fmaf(-mean, mean, Q * (1.0f / 262144.0f));
    const float s = g[c] * rsqrtf(var + 1e-5f);
    sc[c] = s;
    sh[c] = fmaf(-mean, s, be[c]);
  }
}

// ============ recompute chain: STAGE 2 = stats2, 3 = stats3, 4 = final ============
template <int STAGE>
__global__ __launch_bounds__(256) void chain_kernel(
    const float* __restrict__ xyz, const float* __restrict__ dout,
    const int* __restrict__ knn,
    const float* __restrict__ w0, const float* __restrict__ b0,
    const float* __restrict__ w1t, const float* __restrict__ b1,
    const float* __restrict__ w2t, const float* __restrict__ b2,
    const float* __restrict__ sc1, const float* __restrict__ sh1,
    const float* __restrict__ sc2, const float* __restrict__ sh2,
    const float* __restrict__ sc3, const float* __restrict__ sh3,
    float* __restrict__ part, float* __restrict__ outp) {
  __shared__ float f[64 * 256];  // activations, column layout [c][tid]
  const int tid = threadIdx.x;
  const int r = blockIdx.x * 256 + tid;
  const int cid = r >> 5;
  const int b = cid >> 10;
  const int m = cid & 1023;
  const int idx = knn[r];
  const float* pp = xyz + ((size_t)b * NN_ + idx) * 3;
  const float* cc = dout + ((size_t)b * MM_ + m) * 3;
  const float fx = pp[0] - cc[0];
  const float fy = pp[1] - cc[1];
  const float fz = pp[2] - cc[2];
  float acc[64];
#pragma unroll
  for (int o = 0; o < 64; ++o)
    acc[o] = fmaf(w0[o * 3 + 2], fz, fmaf(w0[o * 3 + 1], fy, fmaf(w0[o * 3 + 0], fx, b0[o])));
  // BN1 + ReLU -> LDS (own column only; no barrier needed)
#pragma unroll
  for (int o = 0; o < 64; ++o)
    f[o * 256 + tid] = fmaxf(fmaf(acc[o], sc1[o], sh1[o]), 0.0f);
  // conv2 (output-stationary, uniform weight loads)
  float a2[64];
#pragma unroll
  for (int o = 0; o < 64; ++o) a2[o] = b1[o];
#pragma unroll 4
  for (int c = 0; c < 64; ++c) {
    const float x = f[c * 256 + tid];
#pragma unroll
    for (int o = 0; o < 64; ++o) a2[o] = fmaf(w1t[c * 64 + o], x, a2[o]);
  }
  const int lane = tid & 63;
  if constexpr (STAGE == 2) {
    float* po = part + ((size_t)blockIdx.x * 4 + (tid >> 6)) * 128;
#pragma unroll
    for (int o = 0; o < 64; ++o) {
      float s = a2[o], q = a2[o] * a2[o];
#pragma unroll
      for (int mk = 1; mk < 64; mk <<= 1) { s += __shfl_xor(s, mk, 64); q += __shfl_xor(q, mk, 64); }
      if (lane == 0) { po[o] = s; po[64 + o] = q; }
    }
    return;
  }
  // BN2 + ReLU -> LDS (overwrite own column)
#pragma unroll
  for (int o = 0; o < 64; ++o)
    f[o * 256 + tid] = fmaxf(fmaf(a2[o], sc2[o], sh2[o]), 0.0f);
#pragma unroll
  for (int h = 0; h < 2; ++h) {
    float a3[64];
#pragma unroll
    for (int o = 0; o < 64; ++o) a3[o] = b2[h * 64 + o];
#pragma unroll 4
    for (int c = 0; c < 64; ++c) {
      const float x = f[c * 256 + tid];
#pragma unroll
      for (int o = 0; o < 64; ++o) a3[o] = fmaf(w2t[c * 128 + h * 64 + o], x, a3[o]);
    }
    if constexpr (STAGE == 3) {
      float* po = part + ((size_t)blockIdx.x * 4 + (tid >> 6)) * 256;
#pragma unroll
      for (int o = 0; o < 64; ++o) {
        float s = a3[o], q = a3[o] * a3[o];
#pragma unroll
        for (int mk = 1; mk < 64; mk <<= 1) { s += __shfl_xor(s, mk, 64); q += __shfl_xor(q, mk, 64); }
        if (lane == 0) { po[h * 64 + o] = s; po[128 + h * 64 + o] = q; }
      }
    } else {
      // BN3 + ReLU + max over k (32 lanes) + transposed store
#pragma unroll
      for (int o = 0; o < 64; ++o) {
        float v = fmaxf(fmaf(a3[o], sc3[h * 64 + o], sh3[h * 64 + o]), 0.0f);
#pragma unroll
        for (int mk = 1; mk < 32; mk <<= 1) v = fmaxf(v, __shfl_xor(v, mk, 64));
        if ((lane & 31) == 0)
          outp[24576 + (size_t)b * 131072 + (size_t)(h * 64 + o) * 1024 + m] = v;
      }
    }
  }
}

// ============================ launch =============================
extern "C" void kernel_launch(void* const* d_in, const int* in_sizes, int n_in,
                              void* d_out, int out_size, void* d_ws, size_t ws_size,
                              hipStream_t stream) {
  const float* xyz = (const float*)d_in[0];
  const float* w0 = (const float*)d_in[1];
  const float* b0 = (const float*)d_in[2];
  const float* g0 = (const float*)d_in[3];
  const float* be0 = (const float*)d_in[4];
  const float* w1 = (const float*)d_in[5];
  const float* b1 = (const float*)d_in[6];
  const float* g1 = (const float*)d_in[7];
  const float* be1 = (const float*)d_in[8];
  const float* w2 = (const float*)d_in[9];
  const float* b2 = (const float*)d_in[10];
  const float* g2 = (const float*)d_in[11];
  const float* be2 = (const float*)d_in[12];
  float* out = (float*)d_out;
  char* ws = (char*)d_ws;

  // ws layout (~9.5 MB total):
  int* knn = (int*)ws;                                   // [8192][32] ints
  float* part1 = (float*)(ws + (size_t)1 * (1 << 20));   // [4096][128]
  float* part2 = (float*)(ws + (size_t)3 * (1 << 20));   // [4096][128]
  float* part3 = (float*)(ws + (size_t)5 * (1 << 20));   // [4096][256]
  float* sc1 = (float*)(ws + (size_t)9 * (1 << 20));
  float* sh1 = sc1 + 64;
  float* sc2 = sh1 + 64;
  float* sh2 = sc2 + 64;
  float* sc3 = sh2 + 64;
  float* sh3 = sc3 + 128;
  float* w1t = sh3 + 128;
  float* w2t = w1t + 4096;

  fps_kernel<<<8, 256, 0, stream>>>(xyz, out);
  knn_kernel<<<8192, 64, 0, stream>>>(xyz, out, knn);
  prep_kernel<<<32, 256, 0, stream>>>(w1, w2, w1t, w2t);
  s1_kernel<<<1024, 256, 0, stream>>>(xyz, out, knn, w0, b0, part1);
  rstat_kernel<<<64, 256, 0, stream>>>(part1, 64, g0, be0, sc1, sh1);
  chain_kernel<2><<<1024, 256, 0, stream>>>(xyz, out, knn, w0, b0, w1t, b1, w2t, b2,
                                            sc1, sh1, sc2, sh2, sc3, sh3, part2, out);
  rstat_kernel<<<64, 256, 0, stream>>>(part2, 64, g1, be1, sc2, sh2);
  chain_kernel<3><<<1024, 256, 0, stream>>>(xyz, out, knn, w0, b0, w1t, b1, w2t, b2,
                                            sc1, sh1, sc2, sh2, sc3, sh3, part3, out);
  rstat_kernel<<<128, 256, 0, stream>>>(part3, 128, g2, be2, sc3, sh3);
  chain_kernel<4><<<1024, 256, 0, stream>>>(xyz, out, knn, w0, b0, w1t, b1, w2t, b2,
                                            sc1, sh1, sc2, sh2, sc3, sh3, part3, out);
}